// Round 5
// baseline (191.687 us; speedup 1.0000x reference)
//
#include <hip/hip_runtime.h>
#include <cmath>

// Problem constants (fixed by the reference).
constexpr int B  = 4096;
constexpr int D  = 768;
constexpr int P  = 96;
constexpr int C  = 256;
constexpr int SD = 8;    // D / P

constexpr int TPB   = 192;  // 3 waves; wave w handles partition p0 + w
constexpr int PT    = 3;    // partitions per block
constexpr int RT    = 256;  // rows per block
constexpr int ROWS  = 4;    // rows per thread
constexpr int VROW  = 28;   // padded LDS row stride (24 used), 112 B, 16B-aligned

// ---- numpy fp32 emulation helpers (exact path, validated absmax=0) ---------
__device__ __forceinline__ float tree8(float q0, float q1, float q2, float q3,
                                       float q4, float q5, float q6, float q7)
{
#pragma clang fp contract(off)
    return ((q0 + q1) + (q2 + q3)) + ((q4 + q5) + (q6 + q7));
}

__device__ __forceinline__ float proba_np(const float* __restrict__ cbf,
                                          const float* __restrict__ csq,
                                          int c, float4 va, float4 vb, float vsq)
{
#pragma clang fp contract(off)
    float4 ca = ((const float4*)cbf)[2 * c];
    float4 cb = ((const float4*)cbf)[2 * c + 1];
    float p0 = va.x * ca.x, p1 = va.y * ca.y, p2 = va.z * ca.z, p3 = va.w * ca.w;
    float p4 = vb.x * cb.x, p5 = vb.y * cb.y, p6 = vb.z * cb.z, p7 = vb.w * cb.w;
    float l0 = p0 + p4, l1 = p1 + p5, l2 = p2 + p6, l3 = p3 + p7;
    float vc = (l0 + l2) + (l1 + l3);
    float tt = vsq - 2.0f * vc;
    float u  = tt + csq[c];
    return -u;
}

// Exact numpy-order argmax incl. softmax tie path (validated rounds 1-4).
__device__ __attribute__((noinline))
int exact_search(const float* __restrict__ cbf, const float* __restrict__ csq,
                 float4 va, float4 vb, float vsq)
{
#pragma clang fp contract(off)
    float best = -3.402823466e38f, second = -3.402823466e38f;
    int bi = 0;
    for (int c = 0; c < C; ++c) {
        float pr = proba_np(cbf, csq, c, va, vb, vsq);
        if (pr > best)        { second = best; best = pr; bi = c; }
        else if (pr > second) { second = pr; }
    }
    int idx = bi;

    if (best - second <= 1.0e-6f) {
        float m = best;
        float r0[8] = {0,0,0,0,0,0,0,0};
        float r1[8] = {0,0,0,0,0,0,0,0};
        for (int cg = 0; cg < 16; ++cg) {
            #pragma unroll
            for (int j = 0; j < 8; ++j) {
                float pr = proba_np(cbf, csq, cg * 8 + j, va, vb, vsq);
                r0[j] += expf(pr - m);
            }
        }
        for (int cg = 16; cg < 32; ++cg) {
            #pragma unroll
            for (int j = 0; j < 8; ++j) {
                float pr = proba_np(cbf, csq, cg * 8 + j, va, vb, vsq);
                r1[j] += expf(pr - m);
            }
        }
        float sum = tree8(r0[0],r0[1],r0[2],r0[3],r0[4],r0[5],r0[6],r0[7])
                  + tree8(r1[0],r1[1],r1[2],r1[3],r1[4],r1[5],r1[6],r1[7]);
        float abest = -1.0f;
        int   ai    = 0;
        for (int c = 0; c < C; ++c) {
            float pr = proba_np(cbf, csq, c, va, vb, vsq);
            float e  = expf(pr - m);
            float a  = e / sum;
            if (a > abest) { abest = a; ai = c; }
        }
        idx = ai;
    }
    return idx;
}

// Block = 3 waves x 64 lanes: 256 rows x 3 partitions (p0 = 3*blockIdx.x + w).
// vecs/out move through a padded LDS tile as contiguous 96 B row-runs (full
// 64B lines, coalesced); scoring reads centroids as wave-uniform LDS
// broadcasts, register-staged 4 centroids at a time to amortize LDS latency.
__global__ __launch_bounds__(TPB, 4)
void pq_coal_kernel(const float* __restrict__ vecs,
                    const float* __restrict__ codebook,
                    float* __restrict__ out)
{
    __shared__ float vt  [RT * VROW];      // 28 KB row tile (in, then out)
    __shared__ float cbl [PT * C * SD];    // 24 KB codebooks for 3 partitions
    __shared__ float csqn[PT * C];         //  3 KB ||c||^2 numpy order
    __shared__ float csqh[PT * C];         //  3 KB -0.5*csq

    const int t  = threadIdx.x;
    const int w  = t >> 6;                 // wave id = local partition 0..2
    const int l  = t & 63;
    const int bx = blockIdx.x;             // 0..31 (p-tile)
    const int rowbase = blockIdx.y * RT;   // 0..15 chunks of 256 rows
    const int t6  = t / 6;                 // 0..31
    const int tm6 = t - 6 * t6;            // 0..5

    // ---- stage codebooks: 3*2048 floats = 1536 float4, 8 per thread ----
    {
        const float4* src = (const float4*)(codebook + (size_t)(3 * bx) * C * SD);
        float4* dst = (float4*)cbl;
        #pragma unroll
        for (int k = 0; k < 8; ++k)
            dst[t + TPB * k] = src[t + TPB * k];
    }
    // ---- stage row tile: 256 rows x 6 float4 (96 B per row, coalesced) ----
    {
        const float4* src = (const float4*)vecs;
        #pragma unroll
        for (int k = 0; k < 8; ++k) {
            int row = k * 32 + t6;
            float4 x = src[(size_t)(rowbase + row) * (D / 4) + bx * 6 + tm6];
            *(float4*)(vt + row * VROW + tm6 * 4) = x;
        }
    }
    __syncthreads();

    // ---- csq (numpy order) + fast seed: 768 centroids, 4 per thread ----
    #pragma unroll
    for (int k = 0; k < 4; ++k) {
        int c = t + TPB * k;               // 0..767
        const float* cc = cbl + c * SD;
        float q0 = cc[0]*cc[0], q1 = cc[1]*cc[1], q2 = cc[2]*cc[2], q3 = cc[3]*cc[3];
        float q4 = cc[4]*cc[4], q5 = cc[5]*cc[5], q6 = cc[6]*cc[6], q7 = cc[7]*cc[7];
        float s = tree8(q0,q1,q2,q3,q4,q5,q6,q7);
        csqn[c] = s;
        csqh[c] = -0.5f * s;
    }

    // ---- read this thread's 4 sub-vectors from the tile (own cells) ----
    float4 va[ROWS], vb[ROWS];
    #pragma unroll
    for (int r = 0; r < ROWS; ++r) {
        const float* vp = vt + (64 * r + l) * VROW + w * SD;
        va[r] = *(const float4*)(vp);
        vb[r] = *(const float4*)(vp + 4);
    }
    __syncthreads();

    // ---- fast scoring: 256 centroids, 4-wide register staging ----
    const float4* CB = (const float4*)(cbl + w * C * SD);
    const float*  CH = csqh + w * C;

    float best[ROWS], second[ROWS];
    int   bi[ROWS];
    #pragma unroll
    for (int r = 0; r < ROWS; ++r) {
        best[r] = -3.402823466e38f; second[r] = -3.402823466e38f; bi[r] = 0;
    }

    for (int c = 0; c < C; c += 4) {
        float4 A[4], Bv[4];
        float  H[4];
        #pragma unroll
        for (int u = 0; u < 4; ++u) {       // issue all 12 LDS reads first
            A[u]  = CB[2 * (c + u)];
            Bv[u] = CB[2 * (c + u) + 1];
            H[u]  = CH[c + u];
        }
        #pragma unroll
        for (int u = 0; u < 4; ++u) {
            #pragma unroll
            for (int r = 0; r < ROWS; ++r) {
                float s = fmaf(va[r].x, A[u].x, H[u]);
                s = fmaf(va[r].y, A[u].y, s);
                s = fmaf(va[r].z, A[u].z, s);
                s = fmaf(va[r].w, A[u].w, s);
                s = fmaf(vb[r].x, Bv[u].x, s);
                s = fmaf(vb[r].y, Bv[u].y, s);
                s = fmaf(vb[r].z, Bv[u].z, s);
                s = fmaf(vb[r].w, Bv[u].w, s);
                bool gt = s > best[r];
                second[r] = fmaxf(second[r], fminf(s, best[r]));
                bi[r]     = gt ? (c + u) : bi[r];
                best[r]   = fmaxf(s, best[r]);
            }
        }
    }

    // ---- resolve (rare exact path) + write centroids back into the tile ----
    const float* cbf_w = cbl + w * C * SD;
    const float* csq_w = csqn + w * C;
    #pragma unroll
    for (int r = 0; r < ROWS; ++r) {
        int idx = bi[r];
        if (best[r] - second[r] <= 2.0e-5f) {
            float q0 = va[r].x*va[r].x, q1 = va[r].y*va[r].y,
                  q2 = va[r].z*va[r].z, q3 = va[r].w*va[r].w;
            float q4 = vb[r].x*vb[r].x, q5 = vb[r].y*vb[r].y,
                  q6 = vb[r].z*vb[r].z, q7 = vb[r].w*vb[r].w;
            float vsq = tree8(q0,q1,q2,q3,q4,q5,q6,q7);
            idx = exact_search(cbf_w, csq_w, va[r], vb[r], vsq);
        }
        float4 o0 = ((const float4*)cbf_w)[2 * idx];
        float4 o1 = ((const float4*)cbf_w)[2 * idx + 1];
        float* op = vt + (64 * r + l) * VROW + w * SD;   // own cells
        *(float4*)(op)     = o0;
        *(float4*)(op + 4) = o1;
    }
    __syncthreads();

    // ---- coalesced dump: 256 rows x 6 float4 ----
    {
        float4* dst = (float4*)out;
        #pragma unroll
        for (int k = 0; k < 8; ++k) {
            int row = k * 32 + t6;
            float4 x = *(const float4*)(vt + row * VROW + tm6 * 4);
            dst[(size_t)(rowbase + row) * (D / 4) + bx * 6 + tm6] = x;
        }
    }
}

extern "C" void kernel_launch(void* const* d_in, const int* in_sizes, int n_in,
                              void* d_out, int out_size, void* d_ws, size_t ws_size,
                              hipStream_t stream)
{
    const float* vecs     = (const float*)d_in[0];  // [B, D] fp32
    const float* codebook = (const float*)d_in[1];  // [P, C, SD] fp32
    float*       out      = (float*)d_out;          // [B, D] fp32

    dim3 grid(P / PT, B / RT);   // (32, 16) = 512 blocks, exactly 2 per CU
    dim3 block(TPB);
    pq_coal_kernel<<<grid, block, 0, stream>>>(vecs, codebook, out);
}